// Round 1
// baseline (128.569 us; speedup 1.0000x reference)
//
#include <hip/hip_runtime.h>
#include <hip/hip_bf16.h>

#define B_    32
#define NBB_  16
#define C_    1024
#define H_    22
#define W_    22
#define NROI  512
#define KCONV 9216
#define SCALE_ (1.0f/16.0f)
#define EPS_  1e-5f

using f32x4  = __attribute__((ext_vector_type(4))) float;
using bf16x8 = __attribute__((ext_vector_type(8))) short;

__device__ __forceinline__ unsigned short f2bf(float f) {
  union { float f; unsigned u; } x; x.f = f;
  unsigned r = x.u + 0x7fffu + ((x.u >> 16) & 1u);   // RNE
  return (unsigned short)(r >> 16);
}

__device__ __forceinline__ float hat_int(float t) {
  t = fminf(fmaxf(t, -1.f), 1.f);
  return t + 0.5f - 0.5f * t * fabsf(t);
}

// ---------------- K0: per-ROI separable integral weights (1/area folded into Wx)
__global__ __launch_bounds__(32) void prep_rois(const float* __restrict__ bbox,
                                                float* __restrict__ wy,
                                                float* __restrict__ wx) {
  int r = blockIdx.x;                     // 0..511  (b*NBB+n)
  float4 bb = ((const float4*)bbox)[r];
  float x1 = bb.x * SCALE_, y1 = bb.y * SCALE_;
  float x2 = (bb.x + bb.z) * SCALE_, y2 = (bb.y + bb.w) * SCALE_;
  float bw = (x2 - x1) / 3.f, bh = (y2 - y1) / 3.f;
  float area = fmaxf(bw * bh, 0.f);
  float inv = area > 0.f ? 1.f / fmaxf(area, 1e-12f) : 0.f;
  int i = threadIdx.x;
  if (i < 22) {
    float fi = (float)i;
#pragma unroll
    for (int q = 0; q < 3; ++q) {
      float sy = y1 + q * bh;
      wy[r*66 + q*22 + i] = hat_int(sy + bh - fi) - hat_int(sy - fi);
      float sx = x1 + q * bw;
      wx[r*66 + q*22 + i] = (hat_int(sx + bw - fi) - hat_int(sx - fi)) * inv;
    }
  }
}

// ---------------- K1: fp32 -> bf16 converter (8 elems/thread)
__global__ __launch_bounds__(256) void cvt_bf16(const float* __restrict__ src,
                                                unsigned short* __restrict__ dst, int n8) {
  int i = blockIdx.x * 256 + threadIdx.x;
  if (i >= n8) return;
  float4 a = ((const float4*)src)[2*i];
  float4 b = ((const float4*)src)[2*i + 1];
  uint4 pk;
  pk.x = (unsigned)f2bf(a.x) | ((unsigned)f2bf(a.y) << 16);
  pk.y = (unsigned)f2bf(a.z) | ((unsigned)f2bf(a.w) << 16);
  pk.z = (unsigned)f2bf(b.x) | ((unsigned)f2bf(b.y) << 16);
  pk.w = (unsigned)f2bf(b.z) | ((unsigned)f2bf(b.w) << 16);
  ((uint4*)dst)[i] = pk;
}

// ---------------- K2: PrRoI pooling. Block = (b, 16-channel chunk); 256 thr = 16 roi x 16 ch.
// Writes X[512][9216] bf16, k = c*9 + q*3 + p  (matches conv_w OIHW flattening).
__global__ __launch_bounds__(256) void pool_kernel(const float* __restrict__ feat,
                                                   const float* __restrict__ wyg,
                                                   const float* __restrict__ wxg,
                                                   unsigned short* __restrict__ X) {
  __shared__ __align__(16) float featS[16 * 484];
  __shared__ float wyS[NBB_ * 66];
  __shared__ float wxS[NBB_ * 66];
  int tid = threadIdx.x;
  int cb = blockIdx.x;                    // channel chunk 0..63
  int b  = blockIdx.y;                    // batch 0..31
  const float4* f4 = (const float4*)(feat + ((size_t)b * C_ + (size_t)cb * 16) * 484);
#pragma unroll
  for (int i = 0; i < 8; ++i) {           // 16*484/4 = 1936 float4 loads
    int idx = tid + i * 256;
    if (idx < 1936) ((float4*)featS)[idx] = f4[idx];
  }
  const float* wysrc = wyg + (size_t)b * NBB_ * 66;
  const float* wxsrc = wxg + (size_t)b * NBB_ * 66;
  for (int idx = tid; idx < NBB_ * 66; idx += 256) { wyS[idx] = wysrc[idx]; wxS[idx] = wxsrc[idx]; }
  __syncthreads();

  int cl = tid & 15, n = tid >> 4;
  const float* fp = featS + cl * 484;
  float wxr[3][22];
#pragma unroll
  for (int p = 0; p < 3; ++p)
#pragma unroll
    for (int w = 0; w < 22; ++w) wxr[p][w] = wxS[n*66 + p*22 + w];

  float out[3][3] = {};
  for (int h = 0; h < 22; ++h) {
    float wy0 = wyS[n*66 + h], wy1 = wyS[n*66 + 22 + h], wy2 = wyS[n*66 + 44 + h];
    float cs0 = 0.f, cs1 = 0.f, cs2 = 0.f;
#pragma unroll
    for (int w = 0; w < 22; ++w) {
      float f = fp[h*22 + w];
      cs0 += f * wxr[0][w];
      cs1 += f * wxr[1][w];
      cs2 += f * wxr[2][w];
    }
    out[0][0] += wy0*cs0; out[0][1] += wy0*cs1; out[0][2] += wy0*cs2;
    out[1][0] += wy1*cs0; out[1][1] += wy1*cs1; out[1][2] += wy1*cs2;
    out[2][0] += wy2*cs0; out[2][1] += wy2*cs1; out[2][2] += wy2*cs2;
  }
  unsigned short* xp = X + (size_t)(b*NBB_ + n) * KCONV + (size_t)(cb*16 + cl) * 9;
#pragma unroll
  for (int q = 0; q < 3; ++q)
#pragma unroll
    for (int p = 0; p < 3; ++p) xp[q*3 + p] = f2bf(out[q][p]);
}

// ---------------- K3: NT GEMM, bf16 MFMA 16x16x32, 64x64 tile, 4 waves (2x2), BK=32, split-K.
// Writes fp32 partials Cp[z][M][N].
__global__ __launch_bounds__(256) void gemm_nt(const unsigned short* __restrict__ A,
                                               const unsigned short* __restrict__ Bm,
                                               float* __restrict__ Cp,
                                               int M, int N, int K, int kChunk) {
  __shared__ __align__(16) unsigned short As[64][40];
  __shared__ __align__(16) unsigned short Bs[64][40];
  int tid = threadIdx.x;
  int lane = tid & 63, wid = tid >> 6;
  int wm = wid >> 1, wn = wid & 1;
  int l15 = lane & 15, kg = lane >> 4;
  int nt = blockIdx.x, mt = blockIdx.y, z = blockIdx.z;
  int kbeg = z * kChunk;
  int kend = kbeg + kChunk; if (kend > K) kend = K;
  int srow = tid >> 2, sseg = tid & 3;
  const unsigned short* aG = A  + (size_t)(mt*64 + srow) * K + sseg * 8;
  const unsigned short* bG = Bm + (size_t)(nt*64 + srow) * K + sseg * 8;
  f32x4 acc[2][2] = {};

  for (int k0 = kbeg; k0 < kend; k0 += 32) {
    uint4 av = *(const uint4*)(aG + k0);
    uint4 bv = *(const uint4*)(bG + k0);
    __syncthreads();
    *(uint4*)&As[srow][sseg*8] = av;
    *(uint4*)&Bs[srow][sseg*8] = bv;
    __syncthreads();
    bf16x8 a0 = *(const bf16x8*)&As[wm*32 +      l15][kg*8];
    bf16x8 a1 = *(const bf16x8*)&As[wm*32 + 16 + l15][kg*8];
    bf16x8 b0 = *(const bf16x8*)&Bs[wn*32 +      l15][kg*8];
    bf16x8 b1 = *(const bf16x8*)&Bs[wn*32 + 16 + l15][kg*8];
    acc[0][0] = __builtin_amdgcn_mfma_f32_16x16x32_bf16(a0, b0, acc[0][0], 0, 0, 0);
    acc[0][1] = __builtin_amdgcn_mfma_f32_16x16x32_bf16(a0, b1, acc[0][1], 0, 0, 0);
    acc[1][0] = __builtin_amdgcn_mfma_f32_16x16x32_bf16(a1, b0, acc[1][0], 0, 0, 0);
    acc[1][1] = __builtin_amdgcn_mfma_f32_16x16x32_bf16(a1, b1, acc[1][1], 0, 0, 0);
  }

  float* cp = Cp + ((size_t)z * M + (size_t)mt * 64) * N + (size_t)nt * 64;
#pragma unroll
  for (int fm = 0; fm < 2; ++fm)
#pragma unroll
    for (int fn = 0; fn < 2; ++fn)
#pragma unroll
      for (int r = 0; r < 4; ++r) {
        int row = wm*32 + fm*16 + kg*4 + r;     // C/D: row = (lane>>4)*4 + reg
        int col = wn*32 + fn*16 + l15;          //      col = lane & 15
        cp[(size_t)row * N + col] = acc[fm][fn][r];
      }
}

// ---------------- K4: split-K reduce + epilogue. MODE 0: BN+ReLU->bf16; 1: bias+ReLU->bf16; 2: bias->fp32
template<int MODE>
__global__ __launch_bounds__(256) void epi(const float* __restrict__ Cp, int SK, int MN4, int N,
                                           const float* __restrict__ bias,
                                           const float* __restrict__ g,
                                           const float* __restrict__ be,
                                           const float* __restrict__ mu,
                                           const float* __restrict__ var,
                                           unsigned short* __restrict__ outb,
                                           float* __restrict__ outf) {
  int i = blockIdx.x * 256 + threadIdx.x;
  if (i >= MN4) return;
  float4 s = ((const float4*)Cp)[i];
  for (int z = 1; z < SK; ++z) {
    float4 t = ((const float4*)Cp)[(size_t)z * MN4 + i];
    s.x += t.x; s.y += t.y; s.z += t.z; s.w += t.w;
  }
  int n0 = (i * 4) % N;                    // N is 1024 or 512; 4 | N
  float v[4] = {s.x, s.y, s.z, s.w};
  if (MODE == 0) {
    unsigned short o[4];
#pragma unroll
    for (int j = 0; j < 4; ++j) {
      int n = n0 + j;
      float sc = g[n] * rsqrtf(var[n] + EPS_);
      float t = (v[j] + bias[n] - mu[n]) * sc + be[n];
      o[j] = f2bf(fmaxf(t, 0.f));
    }
    uint2 pk; pk.x = (unsigned)o[0] | ((unsigned)o[1] << 16);
    pk.y = (unsigned)o[2] | ((unsigned)o[3] << 16);
    *(uint2*)&outb[(size_t)i * 4] = pk;
  } else if (MODE == 1) {
    unsigned short o[4];
#pragma unroll
    for (int j = 0; j < 4; ++j) o[j] = f2bf(fmaxf(v[j] + bias[n0 + j], 0.f));
    uint2 pk; pk.x = (unsigned)o[0] | ((unsigned)o[1] << 16);
    pk.y = (unsigned)o[2] | ((unsigned)o[3] << 16);
    *(uint2*)&outb[(size_t)i * 4] = pk;
  } else {
    float4 o;
    o.x = v[0] + bias[n0];     o.y = v[1] + bias[n0 + 1];
    o.z = v[2] + bias[n0 + 2]; o.w = v[3] + bias[n0 + 3];
    ((float4*)outf)[i] = o;
  }
}

extern "C" void kernel_launch(void* const* d_in, const int* in_sizes, int n_in,
                              void* d_out, int out_size, void* d_ws, size_t ws_size,
                              hipStream_t stream) {
  const float* feat   = (const float*)d_in[0];
  const float* bbox   = (const float*)d_in[1];
  const float* conv_w = (const float*)d_in[2];
  const float* conv_b = (const float*)d_in[3];
  const float* gamma  = (const float*)d_in[4];
  const float* beta   = (const float*)d_in[5];
  const float* mean   = (const float*)d_in[6];
  const float* var    = (const float*)d_in[7];
  const float* w1     = (const float*)d_in[8];
  const float* b1     = (const float*)d_in[9];
  const float* w2     = (const float*)d_in[10];
  const float* b2     = (const float*)d_in[11];
  const float* w3     = (const float*)d_in[12];
  const float* b3     = (const float*)d_in[13];

  char* ws = (char*)d_ws;
  float*          wy  = (float*)(ws);                       //   135168 B
  float*          wx  = (float*)(ws + 135168);              //   135168 B
  unsigned short* Xb  = (unsigned short*)(ws + 270336);     //  9437184 B  [512][9216] bf16
  unsigned short* Wfb = (unsigned short*)(ws + 9707520);    // 18874368 B  [1024][9216] bf16
  unsigned short* w1b = (unsigned short*)(ws + 28581888);   //  1048576 B
  unsigned short* w2b = (unsigned short*)(ws + 29630464);   //   524288 B
  unsigned short* w3b = (unsigned short*)(ws + 30154752);   //   524288 B
  float*          part= (float*)(ws + 30679040);            //  8388608 B  [4][512][1024] f32
  unsigned short* H0  = (unsigned short*)(ws + 39067648);   //  1048576 B  [512][1024] bf16
  unsigned short* H1  = (unsigned short*)(ws + 40116224);   //   524288 B
  unsigned short* H2  = (unsigned short*)(ws + 40640512);   //   524288 B  (total 41164800 B)

  prep_rois<<<NROI, 32, 0, stream>>>(bbox, wy, wx);
  cvt_bf16<<<(1179648 + 255) / 256, 256, 0, stream>>>(conv_w, Wfb, 1179648); // 9.44M elems
  cvt_bf16<<<(65536 + 255) / 256, 256, 0, stream>>>(w1, w1b, 65536);
  cvt_bf16<<<(32768 + 255) / 256, 256, 0, stream>>>(w2, w2b, 32768);
  cvt_bf16<<<(32768 + 255) / 256, 256, 0, stream>>>(w3, w3b, 32768);
  pool_kernel<<<dim3(64, 32), 256, 0, stream>>>(feat, wy, wx, Xb);

  // conv GEMM: [512,9216] x [1024,9216]^T, SK=4
  gemm_nt<<<dim3(16, 8, 4), 256, 0, stream>>>(Xb, Wfb, part, 512, 1024, 9216, 2304);
  epi<0><<<(131072 + 255) / 256, 256, 0, stream>>>(part, 4, 131072, 1024,
      conv_b, gamma, beta, mean, var, H0, nullptr);

  // MLP1: [512,1024] x [512,1024]^T, SK=4
  gemm_nt<<<dim3(8, 8, 4), 256, 0, stream>>>(H0, w1b, part, 512, 512, 1024, 256);
  epi<1><<<(65536 + 255) / 256, 256, 0, stream>>>(part, 4, 65536, 512,
      b1, nullptr, nullptr, nullptr, nullptr, H1, nullptr);

  // MLP2: [512,512] x [512,512]^T, SK=4
  gemm_nt<<<dim3(8, 8, 4), 256, 0, stream>>>(H1, w2b, part, 512, 512, 512, 128);
  epi<1><<<(65536 + 255) / 256, 256, 0, stream>>>(part, 4, 65536, 512,
      b2, nullptr, nullptr, nullptr, nullptr, H2, nullptr);

  // MLP3: [512,512] x [512,512]^T, SK=4, fp32 out
  gemm_nt<<<dim3(8, 8, 4), 256, 0, stream>>>(H2, w3b, part, 512, 512, 512, 128);
  epi<2><<<(65536 + 255) / 256, 256, 0, stream>>>(part, 4, 65536, 512,
      b3, nullptr, nullptr, nullptr, nullptr, nullptr, (float*)d_out);
}

// Round 2
// 117.477 us; speedup vs baseline: 1.0944x; 1.0944x over previous
//
#include <hip/hip_runtime.h>
#include <hip/hip_bf16.h>

#define B_    32
#define NBB_  16
#define C_    1024
#define H_    22
#define W_    22
#define NROI  512
#define KCONV 9216
#define SCALE_ (1.0f/16.0f)
#define EPS_  1e-5f

using f32x4  = __attribute__((ext_vector_type(4))) float;
using bf16x8 = __attribute__((ext_vector_type(8))) short;

__device__ __forceinline__ unsigned short f2bf(float f) {
  union { float f; unsigned u; } x; x.f = f;
  unsigned r = x.u + 0x7fffu + ((x.u >> 16) & 1u);   // RNE
  return (unsigned short)(r >> 16);
}

__device__ __forceinline__ float hat_int(float t) {
  t = fminf(fmaxf(t, -1.f), 1.f);
  return t + 0.5f - 0.5f * t * fabsf(t);
}

__device__ __forceinline__ void glds16(const void* g, void* l) {
  __builtin_amdgcn_global_load_lds((const __attribute__((address_space(1))) void*)g,
                                   (__attribute__((address_space(3))) void*)l, 16, 0, 0);
}

// ---------------- K0: per-ROI separable integral weights (1/area folded into Wx)
__global__ __launch_bounds__(32) void prep_rois(const float* __restrict__ bbox,
                                                float* __restrict__ wy,
                                                float* __restrict__ wx) {
  int r = blockIdx.x;
  float4 bb = ((const float4*)bbox)[r];
  float x1 = bb.x * SCALE_, y1 = bb.y * SCALE_;
  float x2 = (bb.x + bb.z) * SCALE_, y2 = (bb.y + bb.w) * SCALE_;
  float bw = (x2 - x1) / 3.f, bh = (y2 - y1) / 3.f;
  float area = fmaxf(bw * bh, 0.f);
  float inv = area > 0.f ? 1.f / fmaxf(area, 1e-12f) : 0.f;
  int i = threadIdx.x;
  if (i < 22) {
    float fi = (float)i;
#pragma unroll
    for (int q = 0; q < 3; ++q) {
      float sy = y1 + q * bh;
      wy[r*66 + q*22 + i] = hat_int(sy + bh - fi) - hat_int(sy - fi);
      float sx = x1 + q * bw;
      wx[r*66 + q*22 + i] = (hat_int(sx + bw - fi) - hat_int(sx - fi)) * inv;
    }
  }
}

// ---------------- K1: fp32 -> bf16 converter
__global__ __launch_bounds__(256) void cvt_bf16(const float* __restrict__ src,
                                                unsigned short* __restrict__ dst, int n8) {
  int i = blockIdx.x * 256 + threadIdx.x;
  if (i >= n8) return;
  float4 a = ((const float4*)src)[2*i];
  float4 b = ((const float4*)src)[2*i + 1];
  uint4 pk;
  pk.x = (unsigned)f2bf(a.x) | ((unsigned)f2bf(a.y) << 16);
  pk.y = (unsigned)f2bf(a.z) | ((unsigned)f2bf(a.w) << 16);
  pk.z = (unsigned)f2bf(b.x) | ((unsigned)f2bf(b.y) << 16);
  pk.w = (unsigned)f2bf(b.z) | ((unsigned)f2bf(b.w) << 16);
  ((uint4*)dst)[i] = pk;
}

// ---------------- K2: PrRoI pooling via MFMA.
// Block = (cb: 16-channel chunk, b). 192 threads = 3 waves; wave wid owns nt=wid (np 16*wid..+15).
// Stage-1 (contract w) on MFMA: T[c][np] per h; stage-2 (contract h) on VALU in fragment regs.
__global__ __launch_bounds__(192) void pool_mfma(const float* __restrict__ feat,
                                                 const float* __restrict__ wyg,
                                                 const float* __restrict__ wxg,
                                                 unsigned short* __restrict__ X) {
  __shared__ __align__(16) unsigned short A[22*16*40];   // [h][c][k pad40] bf16, 28160 B
  __shared__ __align__(16) unsigned short Bx[48*32];     // [np][k pad32] bf16, 3072 B
  __shared__ float wyS[16*66];                           // 4224 B
  int tid = threadIdx.x;
  int cb = blockIdx.x, b = blockIdx.y;

  // stage feat -> A (bf16, [h][c][40]); coalesced float4 reads, pairwise packed LDS writes.
  const float4* f4 = (const float4*)(feat + ((size_t)b * C_ + (size_t)cb * 16) * 484);
  for (int i = tid; i < 1936; i += 192) {
    float4 v = f4[i];
    int lin = i * 4;
    {
      int c = lin / 484, rem = lin - c * 484, h = rem / 22, w = rem - h * 22;
      unsigned pk = (unsigned)f2bf(v.x) | ((unsigned)f2bf(v.y) << 16);
      *(unsigned*)&A[(h*16 + c)*40 + w] = pk;               // w is even -> 4B aligned
    }
    {
      int lin2 = lin + 2;
      int c = lin2 / 484, rem = lin2 - c * 484, h = rem / 22, w = rem - h * 22;
      unsigned pk = (unsigned)f2bf(v.z) | ((unsigned)f2bf(v.w) << 16);
      *(unsigned*)&A[(h*16 + c)*40 + w] = pk;
    }
  }
  // zero pad k = 22..31 (read by MFMA)
  for (int z = tid; z < 352*5; z += 192) {
    int row = z / 5, j = z - row * 5;
    *(unsigned*)&A[row*40 + 22 + j*2] = 0u;
  }
  // Bx[np][k]: wx rows, bf16, zero-padded
  if (tid < 48) {
    int n = tid / 3, p = tid - n * 3;
    const float* wxp = wxg + ((size_t)b * 16 + n) * 66 + p * 22;
#pragma unroll
    for (int w = 0; w < 22; w += 2) {
      unsigned pk = (unsigned)f2bf(wxp[w]) | ((unsigned)f2bf(wxp[w+1]) << 16);
      *(unsigned*)&Bx[tid*32 + w] = pk;
    }
#pragma unroll
    for (int w = 22; w < 32; w += 2) *(unsigned*)&Bx[tid*32 + w] = 0u;
  }
  for (int i = tid; i < 1056; i += 192) wyS[i] = wyg[(size_t)b * 1056 + i];
  __syncthreads();

  int lane = tid & 63, wid = tid >> 6;       // wid = nt in 0..2
  int l15 = lane & 15, kg = lane >> 4;
  int np = wid * 16 + l15;
  int n = np / 3, p = np - n * 3;
  bf16x8 bfrag = *(const bf16x8*)&Bx[np*32 + kg*8];
  const float* wyp = wyS + n * 66;
  const unsigned short* Abase = A + l15*40 + kg*8;

  f32x4 zero = {};
  f32x4 acc0 = {}, acc1 = {}, acc2 = {};
  bf16x8 a0 = *(const bf16x8*)&Abase[0];
  f32x4 t0 = __builtin_amdgcn_mfma_f32_16x16x32_bf16(a0, bfrag, zero, 0, 0, 0);
#pragma unroll
  for (int h = 0; h < 21; ++h) {
    bf16x8 a1 = *(const bf16x8*)&Abase[(h+1)*640];
    f32x4 t1 = __builtin_amdgcn_mfma_f32_16x16x32_bf16(a1, bfrag, zero, 0, 0, 0);
    acc0 += t0 * wyp[h];
    acc1 += t0 * wyp[22 + h];
    acc2 += t0 * wyp[44 + h];
    t0 = t1;
  }
  acc0 += t0 * wyp[21];
  acc1 += t0 * wyp[43];
  acc2 += t0 * wyp[65];

  // write X[b*16+n][(cb*16+c)*9 + q*3 + p], c = kg*4 + r
  unsigned short* xrow = X + ((size_t)b*16 + n) * KCONV + (size_t)cb * 144;
#pragma unroll
  for (int r = 0; r < 4; ++r) {
    int base = (kg*4 + r) * 9 + p;
    xrow[base]     = f2bf(acc0[r]);
    xrow[base + 3] = f2bf(acc1[r]);
    xrow[base + 6] = f2bf(acc2[r]);
  }
}

// ---------------- K3: 128x128 NT GEMM, bf16 MFMA, global_load_lds + dbuf + XOR swizzle, split-K.
__global__ __launch_bounds__(256) void gemm128(const unsigned short* __restrict__ A,
                                               const unsigned short* __restrict__ Bm,
                                               float* __restrict__ Cp,
                                               int M, int N, int K, int kChunk) {
  __shared__ __align__(16) unsigned short As[2][4096];   // [buf][128 rows x 32 bf16]
  __shared__ __align__(16) unsigned short Bs[2][4096];
  int tid = threadIdx.x;
  int lane = tid & 63, wid = tid >> 6;
  int wm = wid >> 1, wn = wid & 1;
  int l15 = lane & 15, kg = lane >> 4;
  int nt = blockIdx.x, mt = blockIdx.y, z = blockIdx.z;
  int kbeg = z * kChunk;
  int steps = kChunk / 32;

  // glds source addressing: thread t covers 16B slot (i*256+t); row = slot>>2, slot-in-row = t&3,
  // source slot pre-swizzled by s(row) = (row>>1)&3  (rule #21: swizzle source + read, linear dest)
  int row0 = tid >> 2, row1 = 64 + row0;
  int slot = tid & 3;
  int s0 = slot ^ ((row0 >> 1) & 3);
  int s1 = slot ^ ((row1 >> 1) & 3);
  const unsigned short* ga0 = A  + (size_t)(mt*128 + row0) * K + kbeg + s0*8;
  const unsigned short* ga1 = A  + (size_t)(mt*128 + row1) * K + kbeg + s1*8;
  const unsigned short* gb0 = Bm + (size_t)(nt*128 + row0) * K + kbeg + s0*8;
  const unsigned short* gb1 = Bm + (size_t)(nt*128 + row1) * K + kbeg + s1*8;
  int wbyte = wid * 1024;   // wave-uniform LDS byte offset within each 4096B half

  f32x4 acc[4][4] = {};
  int cur = 0;

#define ISSUE(buf, s) do { int ko = (s) * 32; \
    glds16(ga0 + ko, (char*)&As[(buf)][0] + wbyte); \
    glds16(ga1 + ko, (char*)&As[(buf)][0] + 4096 + wbyte); \
    glds16(gb0 + ko, (char*)&Bs[(buf)][0] + wbyte); \
    glds16(gb1 + ko, (char*)&Bs[(buf)][0] + 4096 + wbyte); } while (0)

  ISSUE(0, 0);
  for (int s = 0; s < steps; ++s) {
    __syncthreads();                       // drains vmcnt: buf[cur] ready; prev reads done
    if (s + 1 < steps) ISSUE(cur ^ 1, s + 1);
    bf16x8 af[4], bfr[4];
#pragma unroll
    for (int fm = 0; fm < 4; ++fm) {
      int fr = wm*64 + fm*16 + l15;
      af[fm] = *(const bf16x8*)&As[cur][fr*32 + ((kg ^ ((fr >> 1) & 3)) << 3)];
    }
#pragma unroll
    for (int fn = 0; fn < 4; ++fn) {
      int fr = wn*64 + fn*16 + l15;
      bfr[fn] = *(const bf16x8*)&Bs[cur][fr*32 + ((kg ^ ((fr >> 1) & 3)) << 3)];
    }
#pragma unroll
    for (int fm = 0; fm < 4; ++fm)
#pragma unroll
      for (int fn = 0; fn < 4; ++fn)
        acc[fm][fn] = __builtin_amdgcn_mfma_f32_16x16x32_bf16(af[fm], bfr[fn], acc[fm][fn], 0, 0, 0);
    cur ^= 1;
  }
#undef ISSUE

  float* cp = Cp + ((size_t)z * M + (size_t)mt * 128) * N + (size_t)nt * 128;
#pragma unroll
  for (int fm = 0; fm < 4; ++fm)
#pragma unroll
    for (int fn = 0; fn < 4; ++fn)
#pragma unroll
      for (int r = 0; r < 4; ++r) {
        int row = wm*64 + fm*16 + kg*4 + r;
        int col = wn*64 + fn*16 + l15;
        cp[(size_t)row * N + col] = acc[fm][fn][r];
      }
}

// ---------------- K3b: 64x64 NT GEMM (MLP sizes), as round 1
__global__ __launch_bounds__(256) void gemm_nt(const unsigned short* __restrict__ A,
                                               const unsigned short* __restrict__ Bm,
                                               float* __restrict__ Cp,
                                               int M, int N, int K, int kChunk) {
  __shared__ __align__(16) unsigned short As[64][40];
  __shared__ __align__(16) unsigned short Bs[64][40];
  int tid = threadIdx.x;
  int lane = tid & 63, wid = tid >> 6;
  int wm = wid >> 1, wn = wid & 1;
  int l15 = lane & 15, kg = lane >> 4;
  int nt = blockIdx.x, mt = blockIdx.y, z = blockIdx.z;
  int kbeg = z * kChunk;
  int kend = kbeg + kChunk; if (kend > K) kend = K;
  int srow = tid >> 2, sseg = tid & 3;
  const unsigned short* aG = A  + (size_t)(mt*64 + srow) * K + sseg * 8;
  const unsigned short* bG = Bm + (size_t)(nt*64 + srow) * K + sseg * 8;
  f32x4 acc[2][2] = {};

  for (int k0 = kbeg; k0 < kend; k0 += 32) {
    uint4 av = *(const uint4*)(aG + k0);
    uint4 bv = *(const uint4*)(bG + k0);
    __syncthreads();
    *(uint4*)&As[srow][sseg*8] = av;
    *(uint4*)&Bs[srow][sseg*8] = bv;
    __syncthreads();
    bf16x8 a0 = *(const bf16x8*)&As[wm*32 +      l15][kg*8];
    bf16x8 a1 = *(const bf16x8*)&As[wm*32 + 16 + l15][kg*8];
    bf16x8 b0 = *(const bf16x8*)&Bs[wn*32 +      l15][kg*8];
    bf16x8 b1 = *(const bf16x8*)&Bs[wn*32 + 16 + l15][kg*8];
    acc[0][0] = __builtin_amdgcn_mfma_f32_16x16x32_bf16(a0, b0, acc[0][0], 0, 0, 0);
    acc[0][1] = __builtin_amdgcn_mfma_f32_16x16x32_bf16(a0, b1, acc[0][1], 0, 0, 0);
    acc[1][0] = __builtin_amdgcn_mfma_f32_16x16x32_bf16(a1, b0, acc[1][0], 0, 0, 0);
    acc[1][1] = __builtin_amdgcn_mfma_f32_16x16x32_bf16(a1, b1, acc[1][1], 0, 0, 0);
  }

  float* cp = Cp + ((size_t)z * M + (size_t)mt * 64) * N + (size_t)nt * 64;
#pragma unroll
  for (int fm = 0; fm < 2; ++fm)
#pragma unroll
    for (int fn = 0; fn < 2; ++fn)
#pragma unroll
      for (int r = 0; r < 4; ++r) {
        int row = wm*32 + fm*16 + kg*4 + r;
        int col = wn*32 + fn*16 + l15;
        cp[(size_t)row * N + col] = acc[fm][fn][r];
      }
}

// ---------------- K4: split-K reduce + epilogue. MODE 0: BN+ReLU->bf16; 1: bias+ReLU->bf16; 2: bias->fp32
template<int MODE>
__global__ __launch_bounds__(256) void epi(const float* __restrict__ Cp, int SK, int MN4, int N,
                                           const float* __restrict__ bias,
                                           const float* __restrict__ g,
                                           const float* __restrict__ be,
                                           const float* __restrict__ mu,
                                           const float* __restrict__ var,
                                           unsigned short* __restrict__ outb,
                                           float* __restrict__ outf) {
  int i = blockIdx.x * 256 + threadIdx.x;
  if (i >= MN4) return;
  float4 s = ((const float4*)Cp)[i];
  for (int z = 1; z < SK; ++z) {
    float4 t = ((const float4*)Cp)[(size_t)z * MN4 + i];
    s.x += t.x; s.y += t.y; s.z += t.z; s.w += t.w;
  }
  int n0 = (i * 4) % N;
  float v[4] = {s.x, s.y, s.z, s.w};
  if (MODE == 0) {
    unsigned short o[4];
#pragma unroll
    for (int j = 0; j < 4; ++j) {
      int n = n0 + j;
      float sc = g[n] * rsqrtf(var[n] + EPS_);
      float t = (v[j] + bias[n] - mu[n]) * sc + be[n];
      o[j] = f2bf(fmaxf(t, 0.f));
    }
    uint2 pk; pk.x = (unsigned)o[0] | ((unsigned)o[1] << 16);
    pk.y = (unsigned)o[2] | ((unsigned)o[3] << 16);
    *(uint2*)&outb[(size_t)i * 4] = pk;
  } else if (MODE == 1) {
    unsigned short o[4];
#pragma unroll
    for (int j = 0; j < 4; ++j) o[j] = f2bf(fmaxf(v[j] + bias[n0 + j], 0.f));
    uint2 pk; pk.x = (unsigned)o[0] | ((unsigned)o[1] << 16);
    pk.y = (unsigned)o[2] | ((unsigned)o[3] << 16);
    *(uint2*)&outb[(size_t)i * 4] = pk;
  } else {
    float4 o;
    o.x = v[0] + bias[n0];     o.y = v[1] + bias[n0 + 1];
    o.z = v[2] + bias[n0 + 2]; o.w = v[3] + bias[n0 + 3];
    ((float4*)outf)[i] = o;
  }
}

extern "C" void kernel_launch(void* const* d_in, const int* in_sizes, int n_in,
                              void* d_out, int out_size, void* d_ws, size_t ws_size,
                              hipStream_t stream) {
  const float* feat   = (const float*)d_in[0];
  const float* bbox   = (const float*)d_in[1];
  const float* conv_w = (const float*)d_in[2];
  const float* conv_b = (const float*)d_in[3];
  const float* gamma  = (const float*)d_in[4];
  const float* beta   = (const float*)d_in[5];
  const float* mean   = (const float*)d_in[6];
  const float* var    = (const float*)d_in[7];
  const float* w1     = (const float*)d_in[8];
  const float* b1     = (const float*)d_in[9];
  const float* w2     = (const float*)d_in[10];
  const float* b2     = (const float*)d_in[11];
  const float* w3     = (const float*)d_in[12];
  const float* b3     = (const float*)d_in[13];

  char* ws = (char*)d_ws;
  float*          wy  = (float*)(ws);                       //   135168 B
  float*          wx  = (float*)(ws + 135168);              //   135168 B
  unsigned short* Xb  = (unsigned short*)(ws + 270336);     //  9437184 B  [512][9216] bf16
  unsigned short* Wfb = (unsigned short*)(ws + 9707520);    // 18874368 B  [1024][9216] bf16
  unsigned short* w1b = (unsigned short*)(ws + 28581888);   //  1048576 B
  unsigned short* w2b = (unsigned short*)(ws + 29630464);   //   524288 B
  unsigned short* w3b = (unsigned short*)(ws + 30154752);   //   524288 B
  float*          part= (float*)(ws + 30679040);            // 16777216 B  [8][512][1024] f32
  unsigned short* H0  = (unsigned short*)(ws + 47456256);   //  1048576 B
  unsigned short* H1  = (unsigned short*)(ws + 48504832);   //   524288 B
  unsigned short* H2  = (unsigned short*)(ws + 49029120);   //   524288 B (total 49553408 B)

  prep_rois<<<NROI, 32, 0, stream>>>(bbox, wy, wx);
  cvt_bf16<<<(1179648 + 255) / 256, 256, 0, stream>>>(conv_w, Wfb, 1179648);
  cvt_bf16<<<(65536 + 255) / 256, 256, 0, stream>>>(w1, w1b, 65536);
  cvt_bf16<<<(32768 + 255) / 256, 256, 0, stream>>>(w2, w2b, 32768);
  cvt_bf16<<<(32768 + 255) / 256, 256, 0, stream>>>(w3, w3b, 32768);
  pool_mfma<<<dim3(64, 32), 192, 0, stream>>>(feat, wy, wx, Xb);

  // conv GEMM: [512,9216] x [1024,9216]^T, 128^2 tiles, SK=8 -> 256 blocks
  gemm128<<<dim3(8, 4, 8), 256, 0, stream>>>(Xb, Wfb, part, 512, 1024, 9216, 1152);
  epi<0><<<(131072 + 255) / 256, 256, 0, stream>>>(part, 8, 131072, 1024,
      conv_b, gamma, beta, mean, var, H0, nullptr);

  // MLP1: [512,1024] x [512,1024]^T, SK=4
  gemm_nt<<<dim3(8, 8, 4), 256, 0, stream>>>(H0, w1b, part, 512, 512, 1024, 256);
  epi<1><<<(65536 + 255) / 256, 256, 0, stream>>>(part, 4, 65536, 512,
      b1, nullptr, nullptr, nullptr, nullptr, H1, nullptr);

  // MLP2: [512,512] x [512,512]^T, SK=4
  gemm_nt<<<dim3(8, 8, 4), 256, 0, stream>>>(H1, w2b, part, 512, 512, 512, 128);
  epi<1><<<(65536 + 255) / 256, 256, 0, stream>>>(part, 4, 65536, 512,
      b2, nullptr, nullptr, nullptr, nullptr, H2, nullptr);

  // MLP3: [512,512] x [512,512]^T, SK=4, fp32 out
  gemm_nt<<<dim3(8, 8, 4), 256, 0, stream>>>(H2, w3b, part, 512, 512, 512, 128);
  epi<2><<<(65536 + 255) / 256, 256, 0, stream>>>(part, 4, 65536, 512,
      b3, nullptr, nullptr, nullptr, nullptr, nullptr, (float*)d_out);
}